// Round 7
// baseline (566.098 us; speedup 1.0000x reference)
//
#include <hip/hip_runtime.h>

// B=4, T=2048, D=1024, DK=128.
// World (PROVEN by R0-R6 evidence): ALL inputs fp32, output fp32.
// R2/R6 produced bit-identical wrong absmax -> compute was correct, store
// format was the only bug. This is the R2 optimized chain with fp32 output.
#define BATCH 4
#define T_SEQ 2048
#define D_MODEL 1024
#define DK 128
#define M_ROWS (BATCH * T_SEQ)          // 8192
#define SCALE 0.088388347648318447f     // 1/sqrt(128)

// ---------------------------------------------------------------------------
// Kernel 1: QKV projection.  grid (M/16, 3), block 256.
// Block = 16 rows x 128 cols of one of {Q,K,V}. x tile (16x1024) fp32 in LDS.
// ---------------------------------------------------------------------------
__global__ __launch_bounds__(256) void qkv_kernel(
    const float* __restrict__ x,
    const float* __restrict__ Wq,
    const float* __restrict__ Wk,
    const float* __restrict__ Wv,
    float* __restrict__ Qg, float* __restrict__ Kg, float* __restrict__ Vg)
{
    const int row0 = blockIdx.x * 16;
    const float* W;
    float* out;
    if (blockIdx.y == 0)      { W = Wq; out = Qg; }
    else if (blockIdx.y == 1) { W = Wk; out = Kg; }
    else                      { W = Wv; out = Vg; }

    __shared__ float xs[16][D_MODEL];   // 64 KB
    const int tid = threadIdx.x;

    const float4* xv = (const float4*)(x + (size_t)row0 * D_MODEL);
    #pragma unroll
    for (int i = 0; i < 16; i++) {
        int idx = tid + 256 * i;            // [0,4096)
        int r = idx >> 8;
        int c = (idx & 255) * 4;
        *(float4*)&xs[r][c] = xv[idx];
    }
    __syncthreads();

    const int n  = tid & 127;   // output column
    const int rh = tid >> 7;    // rows rh*8 .. rh*8+7
    float acc[8] = {0.f, 0.f, 0.f, 0.f, 0.f, 0.f, 0.f, 0.f};

    for (int d = 0; d < D_MODEL; d += 4) {
        float w0 = W[(size_t)(d + 0) * DK + n];
        float w1 = W[(size_t)(d + 1) * DK + n];
        float w2 = W[(size_t)(d + 2) * DK + n];
        float w3 = W[(size_t)(d + 3) * DK + n];
        #pragma unroll
        for (int i = 0; i < 8; i++) {
            const float4 xq = *(const float4*)&xs[rh * 8 + i][d];
            acc[i] += xq.x * w0 + xq.y * w1 + xq.z * w2 + xq.w * w3;
        }
    }
    #pragma unroll
    for (int i = 0; i < 8; i++)
        out[(size_t)(row0 + rh * 8 + i) * DK + n] = acc[i];
}

// ---------------------------------------------------------------------------
// Kernel 2: causal flash attention.  grid (T/32, B), block 256.
// BQ=32 queries, BK=32 key chunk, online softmax, O in registers. LDS ~56 KB.
// ---------------------------------------------------------------------------
__global__ __launch_bounds__(256) void attn_kernel(
    const float* __restrict__ Qg, const float* __restrict__ Kg,
    const float* __restrict__ Vg, float* __restrict__ Og)
{
    const int b  = blockIdx.y;
    const int q0 = blockIdx.x * 32;
    const int tid = threadIdx.x;

    __shared__ float Qs[32][132];
    __shared__ float Ks[32][132];
    __shared__ float Vs[32][132];
    __shared__ float Pt[32][36];      // P transposed: Pt[key][qrow]
    __shared__ float rowm[32], rowl[32], rowa[32];

    {
        const float4* src = (const float4*)(Qg + (size_t)(b * T_SEQ + q0) * DK);
        #pragma unroll
        for (int i = 0; i < 4; i++) {
            int idx = tid + 256 * i;
            int r = idx >> 5, c = (idx & 31) * 4;
            *(float4*)&Qs[r][c] = src[idx];
        }
    }
    if (tid < 32) { rowm[tid] = -1e30f; rowl[tid] = 0.f; }

    const int sr = tid >> 3, cb = tid & 7;    // S: row sr, cols cb+8j
    const int dg = tid & 31, rg = tid >> 5;   // O: rows 4rg..+3, dims 4dg..+3
    const int rr = tid >> 3, hh = tid & 7;    // softmax: 8 lanes per q-row

    float o[4][4];
    #pragma unroll
    for (int i = 0; i < 4; i++)
        #pragma unroll
        for (int j = 0; j < 4; j++) o[i][j] = 0.f;

    __syncthreads();

    const int kend = q0 + 32;
    for (int kc = 0; kc < kend; kc += 32) {
        const float4* ksrc = (const float4*)(Kg + (size_t)(b * T_SEQ + kc) * DK);
        const float4* vsrc = (const float4*)(Vg + (size_t)(b * T_SEQ + kc) * DK);
        #pragma unroll
        for (int i = 0; i < 4; i++) {
            int idx = tid + 256 * i;
            int r = idx >> 5, c = (idx & 31) * 4;
            *(float4*)&Ks[r][c] = ksrc[idx];
            *(float4*)&Vs[r][c] = vsrc[idx];
        }
        __syncthreads();

        // S = Q K^T : 1 row x 4 cols per thread
        float s[4] = {0.f, 0.f, 0.f, 0.f};
        for (int d = 0; d < DK; d += 4) {
            float4 qa = *(const float4*)&Qs[sr][d];
            #pragma unroll
            for (int j = 0; j < 4; j++) {
                float4 kv = *(const float4*)&Ks[cb + 8 * j][d];
                s[j] += qa.x * kv.x + qa.y * kv.y + qa.z * kv.z + qa.w * kv.w;
            }
        }
        #pragma unroll
        for (int j = 0; j < 4; j++) {
            int k_g = kc + cb + 8 * j;
            int q_g = q0 + sr;
            Pt[cb + 8 * j][sr] = (k_g <= q_g) ? s[j] * SCALE : -1e30f;
        }
        __syncthreads();

        // online softmax (8 lanes per q-row)
        float vals[4];
        float mx = -1e30f;
        #pragma unroll
        for (int i = 0; i < 4; i++) {
            vals[i] = Pt[hh + 8 * i][rr];
            mx = fmaxf(mx, vals[i]);
        }
        #pragma unroll
        for (int off = 1; off < 8; off <<= 1)
            mx = fmaxf(mx, __shfl_xor(mx, off, 8));
        float m_old = rowm[rr];
        float m_new = fmaxf(m_old, mx);
        float alpha = __expf(m_old - m_new);
        float lsum = 0.f;
        #pragma unroll
        for (int i = 0; i < 4; i++) {
            float p = __expf(vals[i] - m_new);
            Pt[hh + 8 * i][rr] = p;
            lsum += p;
        }
        #pragma unroll
        for (int off = 1; off < 8; off <<= 1)
            lsum += __shfl_xor(lsum, off, 8);
        if (hh == 0) {
            rowm[rr] = m_new;
            rowl[rr] = rowl[rr] * alpha + lsum;
            rowa[rr] = alpha;
        }
        __syncthreads();

        // O = O*alpha + P V
        float al[4];
        #pragma unroll
        for (int ri = 0; ri < 4; ri++) al[ri] = rowa[4 * rg + ri];
        #pragma unroll
        for (int ri = 0; ri < 4; ri++)
            #pragma unroll
            for (int di = 0; di < 4; di++) o[ri][di] *= al[ri];
        #pragma unroll 4
        for (int j = 0; j < 32; j++) {
            float4 p4 = *(const float4*)&Pt[j][4 * rg];
            float4 v4 = *(const float4*)&Vs[j][4 * dg];
            o[0][0] += p4.x * v4.x; o[0][1] += p4.x * v4.y; o[0][2] += p4.x * v4.z; o[0][3] += p4.x * v4.w;
            o[1][0] += p4.y * v4.x; o[1][1] += p4.y * v4.y; o[1][2] += p4.y * v4.z; o[1][3] += p4.y * v4.w;
            o[2][0] += p4.z * v4.x; o[2][1] += p4.z * v4.y; o[2][2] += p4.z * v4.z; o[2][3] += p4.z * v4.w;
            o[3][0] += p4.w * v4.x; o[3][1] += p4.w * v4.y; o[3][2] += p4.w * v4.z; o[3][3] += p4.w * v4.w;
        }
        __syncthreads();
    }

    #pragma unroll
    for (int ri = 0; ri < 4; ri++) {
        float inv = 1.f / rowl[4 * rg + ri];
        float4 res = make_float4(o[ri][0] * inv, o[ri][1] * inv, o[ri][2] * inv, o[ri][3] * inv);
        *(float4*)&Og[(size_t)(b * T_SEQ + q0 + 4 * rg + ri) * DK + 4 * dg] = res;
    }
}

// ---------------------------------------------------------------------------
// Kernel 3: out = O @ Wo.  grid (M/16, 1024/256), block 256.  *** fp32 out ***
// ---------------------------------------------------------------------------
__global__ __launch_bounds__(256) void outproj_kernel(
    const float* __restrict__ Og, const float* __restrict__ Wo,
    float* __restrict__ out)
{
    const int row0 = blockIdx.x * 16;
    const int n0   = blockIdx.y * 256;
    const int tid  = threadIdx.x;

    __shared__ float Os[16][132];
    {
        const float4* src = (const float4*)(Og + (size_t)row0 * DK);
        #pragma unroll
        for (int i = 0; i < 2; i++) {
            int idx = tid + 256 * i;
            int r = idx >> 5, c = (idx & 31) * 4;
            *(float4*)&Os[r][c] = src[idx];
        }
    }
    __syncthreads();

    const int nc = tid & 63;   // cols n0+nc+64m
    const int rg = tid >> 6;   // rows 4rg..4rg+3
    float acc[4][4];
    #pragma unroll
    for (int i = 0; i < 4; i++)
        #pragma unroll
        for (int j = 0; j < 4; j++) acc[i][j] = 0.f;

    for (int d = 0; d < DK; d += 4) {
        float ovv[4][4];
        #pragma unroll
        for (int ri = 0; ri < 4; ri++) {
            float4 t = *(const float4*)&Os[4 * rg + ri][d];
            ovv[ri][0] = t.x; ovv[ri][1] = t.y; ovv[ri][2] = t.z; ovv[ri][3] = t.w;
        }
        #pragma unroll
        for (int k = 0; k < 4; k++) {
            #pragma unroll
            for (int m = 0; m < 4; m++) {
                float w = Wo[(size_t)(d + k) * D_MODEL + n0 + nc + 64 * m];
                #pragma unroll
                for (int ri = 0; ri < 4; ri++)
                    acc[ri][m] += ovv[ri][k] * w;
            }
        }
    }
    #pragma unroll
    for (int ri = 0; ri < 4; ri++)
        #pragma unroll
        for (int m = 0; m < 4; m++)
            out[(size_t)(row0 + 4 * rg + ri) * D_MODEL + n0 + nc + 64 * m] = acc[ri][m];
}

// ---------------------------------------------------------------------------
extern "C" void kernel_launch(void* const* d_in, const int* in_sizes, int n_in,
                              void* d_out, int out_size, void* d_ws, size_t ws_size,
                              hipStream_t stream)
{
    const float* x  = (const float*)d_in[0];
    const float* Wq = (const float*)d_in[1];
    const float* Wk = (const float*)d_in[2];
    const float* Wv = (const float*)d_in[3];
    const float* Wo = (const float*)d_in[4];
    float* out = (float*)d_out;

    float* ws = (float*)d_ws;
    float* Qg = ws;                         // 8192*128 fp32 = 4 MB
    float* Kg = ws + 1 * 1048576;
    float* Vg = ws + 2 * 1048576;
    float* Og = ws + 3 * 1048576;           // total 16 MB

    qkv_kernel<<<dim3(M_ROWS / 16, 3), 256, 0, stream>>>(x, Wq, Wk, Wv, Qg, Kg, Vg);
    attn_kernel<<<dim3(T_SEQ / 32, BATCH), 256, 0, stream>>>(Qg, Kg, Vg, Og);
    outproj_kernel<<<dim3(M_ROWS / 16, D_MODEL / 256), 256, 0, stream>>>(Og, Wo, out);
}

// Round 8
// 553.976 us; speedup vs baseline: 1.0219x; 1.0219x over previous
//
#include <hip/hip_runtime.h>

// B=4, T=2048, D=1024, DK=128. All inputs fp32, output fp32 (proven R0-R6).
// R7 counters: attn 306us @ 6.3% occupancy (1 block/CU, no rebalancing of the
// causal triangle); qkv 64KB LDS -> 1 block/CU. This round: parallelism.
#define BATCH 4
#define T_SEQ 2048
#define D_MODEL 1024
#define DK 128
#define M_ROWS (BATCH * T_SEQ)          // 8192
#define SCALE 0.088388347648318447f     // 1/sqrt(128)

// ---------------------------------------------------------------------------
// Kernel 1: QKV projection.  grid (M/8, 3), block 256.
// 8-row x-tile (32KB LDS) -> ~5 blocks/CU vs R7's 1. Thread: 4 rows x 1 col.
// ---------------------------------------------------------------------------
__global__ __launch_bounds__(256) void qkv_kernel(
    const float* __restrict__ x,
    const float* __restrict__ Wq,
    const float* __restrict__ Wk,
    const float* __restrict__ Wv,
    float* __restrict__ Qg, float* __restrict__ Kg, float* __restrict__ Vg)
{
    const int row0 = blockIdx.x * 8;
    const float* W;
    float* out;
    if (blockIdx.y == 0)      { W = Wq; out = Qg; }
    else if (blockIdx.y == 1) { W = Wk; out = Kg; }
    else                      { W = Wv; out = Vg; }

    __shared__ float xs[8][D_MODEL];    // 32 KB
    const int tid = threadIdx.x;

    const float4* xv = (const float4*)(x + (size_t)row0 * D_MODEL);
    #pragma unroll
    for (int i = 0; i < 8; i++) {
        int idx = tid + 256 * i;            // [0,2048)
        int r = idx >> 8;                   // 256 float4 per row
        int c = (idx & 255) * 4;
        *(float4*)&xs[r][c] = xv[idx];
    }
    __syncthreads();

    const int n  = tid & 127;   // output column
    const int rh = tid >> 7;    // rows rh*4 .. rh*4+3
    float acc[4] = {0.f, 0.f, 0.f, 0.f};

    for (int d = 0; d < D_MODEL; d += 4) {
        float w0 = W[(size_t)(d + 0) * DK + n];
        float w1 = W[(size_t)(d + 1) * DK + n];
        float w2 = W[(size_t)(d + 2) * DK + n];
        float w3 = W[(size_t)(d + 3) * DK + n];
        #pragma unroll
        for (int i = 0; i < 4; i++) {
            const float4 xq = *(const float4*)&xs[rh * 4 + i][d];  // broadcast
            acc[i] += xq.x * w0 + xq.y * w1 + xq.z * w2 + xq.w * w3;
        }
    }
    #pragma unroll
    for (int i = 0; i < 4; i++)
        out[(size_t)(row0 + rh * 4 + i) * DK + n] = acc[i];
}

// ---------------------------------------------------------------------------
// Kernel 2: causal flash attention.  grid (T/16, B), block 256.
// BQ=16, BK=32. 512 blocks, ~45KB LDS -> 2-3 blocks/CU; heavy tiles launch
// first (reversed index) so greedy dispatch balances the causal triangle.
// ---------------------------------------------------------------------------
__global__ __launch_bounds__(256) void attn_kernel(
    const float* __restrict__ Qg, const float* __restrict__ Kg,
    const float* __restrict__ Vg, float* __restrict__ Og)
{
    const int b  = blockIdx.y;
    const int qt = (T_SEQ / 16 - 1) - blockIdx.x;   // reverse: big tiles first
    const int q0 = qt * 16;
    const int tid = threadIdx.x;

    __shared__ float Qs[16][132];     // 8.4 KB
    __shared__ float Ks[32][132];     // 16.9 KB
    __shared__ float Vs[32][132];     // 16.9 KB
    __shared__ float Pt[32][20];      // P transposed: Pt[key][qrow], 2.5 KB
    __shared__ float rowm[16], rowl[16], rowa[16];

    // stage Q tile: 16x128 fp32 = 512 float4
    {
        const float4* src = (const float4*)(Qg + (size_t)(b * T_SEQ + q0) * DK);
        #pragma unroll
        for (int i = 0; i < 2; i++) {
            int idx = tid + 256 * i;         // [0,512)
            int r = idx >> 5, c = (idx & 31) * 4;
            *(float4*)&Qs[r][c] = src[idx];
        }
    }
    if (tid < 16) { rowm[tid] = -1e30f; rowl[tid] = 0.f; }

    const int sr = tid >> 4, cb = tid & 15;   // S: row sr, keys {cb, cb+16}
    const int dg = tid & 31, rg = tid >> 5;   // O: rows {2rg,2rg+1}, dims 4dg..+3
    const int rr = tid >> 4, hh = tid & 15;   // softmax: 16 lanes per q-row

    float o[2][4] = {{0.f,0.f,0.f,0.f},{0.f,0.f,0.f,0.f}};

    __syncthreads();

    const int kend = q0 + 16;
    for (int kc = 0; kc < kend; kc += 32) {
        // stage K,V chunk: 32x128 fp32 = 1024 float4 each (rows < T always)
        const float4* ksrc = (const float4*)(Kg + (size_t)(b * T_SEQ + kc) * DK);
        const float4* vsrc = (const float4*)(Vg + (size_t)(b * T_SEQ + kc) * DK);
        #pragma unroll
        for (int i = 0; i < 4; i++) {
            int idx = tid + 256 * i;         // [0,1024)
            int r = idx >> 5, c = (idx & 31) * 4;
            *(float4*)&Ks[r][c] = ksrc[idx];
            *(float4*)&Vs[r][c] = vsrc[idx];
        }
        __syncthreads();

        // S = Q K^T : 1 row x 2 keys per thread
        float s0 = 0.f, s1 = 0.f;
        for (int d = 0; d < DK; d += 4) {
            float4 qa = *(const float4*)&Qs[sr][d];
            float4 k0 = *(const float4*)&Ks[cb][d];
            float4 k1 = *(const float4*)&Ks[cb + 16][d];
            s0 += qa.x * k0.x + qa.y * k0.y + qa.z * k0.z + qa.w * k0.w;
            s1 += qa.x * k1.x + qa.y * k1.y + qa.z * k1.z + qa.w * k1.w;
        }
        {
            int q_g = q0 + sr;
            Pt[cb][sr]      = (kc + cb      <= q_g) ? s0 * SCALE : -1e30f;
            Pt[cb + 16][sr] = (kc + cb + 16 <= q_g) ? s1 * SCALE : -1e30f;
        }
        __syncthreads();

        // online softmax: 16 lanes per q-row, 2 keys each
        float v0 = Pt[hh][rr], v1 = Pt[hh + 16][rr];
        float mx = fmaxf(v0, v1);
        #pragma unroll
        for (int off = 1; off < 16; off <<= 1)
            mx = fmaxf(mx, __shfl_xor(mx, off, 16));
        float m_old = rowm[rr];
        float m_new = fmaxf(m_old, mx);
        float alpha = __expf(m_old - m_new);
        float p0 = __expf(v0 - m_new);   // masked (-1e30) -> 0
        float p1 = __expf(v1 - m_new);
        Pt[hh][rr] = p0;
        Pt[hh + 16][rr] = p1;
        float lsum = p0 + p1;
        #pragma unroll
        for (int off = 1; off < 16; off <<= 1)
            lsum += __shfl_xor(lsum, off, 16);
        if (hh == 0) {
            rowm[rr] = m_new;
            rowl[rr] = rowl[rr] * alpha + lsum;
            rowa[rr] = alpha;
        }
        __syncthreads();

        // O = O*alpha + P V   (2 rows x 4 dims per thread)
        float al0 = rowa[2 * rg], al1 = rowa[2 * rg + 1];
        #pragma unroll
        for (int di = 0; di < 4; di++) { o[0][di] *= al0; o[1][di] *= al1; }
        #pragma unroll 4
        for (int j = 0; j < 32; j++) {
            float pa = Pt[j][2 * rg];
            float pb = Pt[j][2 * rg + 1];
            float4 v4 = *(const float4*)&Vs[j][4 * dg];
            o[0][0] += pa * v4.x; o[0][1] += pa * v4.y; o[0][2] += pa * v4.z; o[0][3] += pa * v4.w;
            o[1][0] += pb * v4.x; o[1][1] += pb * v4.y; o[1][2] += pb * v4.z; o[1][3] += pb * v4.w;
        }
        __syncthreads();
    }

    // epilogue: O /= l, store fp32 to workspace
    #pragma unroll
    for (int e = 0; e < 2; e++) {
        float inv = 1.f / rowl[2 * rg + e];
        float4 res = make_float4(o[e][0] * inv, o[e][1] * inv, o[e][2] * inv, o[e][3] * inv);
        *(float4*)&Og[(size_t)(b * T_SEQ + q0 + 2 * rg + e) * DK + 4 * dg] = res;
    }
}

// ---------------------------------------------------------------------------
// Kernel 3: out = O @ Wo.  grid (M/16, 1024/256), block 256. fp32 out.
// (unchanged from R7 — control)
// ---------------------------------------------------------------------------
__global__ __launch_bounds__(256) void outproj_kernel(
    const float* __restrict__ Og, const float* __restrict__ Wo,
    float* __restrict__ out)
{
    const int row0 = blockIdx.x * 16;
    const int n0   = blockIdx.y * 256;
    const int tid  = threadIdx.x;

    __shared__ float Os[16][132];
    {
        const float4* src = (const float4*)(Og + (size_t)row0 * DK);
        #pragma unroll
        for (int i = 0; i < 2; i++) {
            int idx = tid + 256 * i;        // [0,512)
            int r = idx >> 5, c = (idx & 31) * 4;
            *(float4*)&Os[r][c] = src[idx];
        }
    }
    __syncthreads();

    const int nc = tid & 63;   // cols n0+nc+64m
    const int rg = tid >> 6;   // rows 4rg..4rg+3
    float acc[4][4];
    #pragma unroll
    for (int i = 0; i < 4; i++)
        #pragma unroll
        for (int j = 0; j < 4; j++) acc[i][j] = 0.f;

    for (int d = 0; d < DK; d += 4) {
        float ovv[4][4];
        #pragma unroll
        for (int ri = 0; ri < 4; ri++) {
            float4 t = *(const float4*)&Os[4 * rg + ri][d];
            ovv[ri][0] = t.x; ovv[ri][1] = t.y; ovv[ri][2] = t.z; ovv[ri][3] = t.w;
        }
        #pragma unroll
        for (int k = 0; k < 4; k++) {
            #pragma unroll
            for (int m = 0; m < 4; m++) {
                float w = Wo[(size_t)(d + k) * D_MODEL + n0 + nc + 64 * m];
                #pragma unroll
                for (int ri = 0; ri < 4; ri++)
                    acc[ri][m] += ovv[ri][k] * w;
            }
        }
    }
    #pragma unroll
    for (int ri = 0; ri < 4; ri++)
        #pragma unroll
        for (int m = 0; m < 4; m++)
            out[(size_t)(row0 + 4 * rg + ri) * D_MODEL + n0 + nc + 64 * m] = acc[ri][m];
}

// ---------------------------------------------------------------------------
extern "C" void kernel_launch(void* const* d_in, const int* in_sizes, int n_in,
                              void* d_out, int out_size, void* d_ws, size_t ws_size,
                              hipStream_t stream)
{
    const float* x  = (const float*)d_in[0];
    const float* Wq = (const float*)d_in[1];
    const float* Wk = (const float*)d_in[2];
    const float* Wv = (const float*)d_in[3];
    const float* Wo = (const float*)d_in[4];
    float* out = (float*)d_out;

    float* ws = (float*)d_ws;
    float* Qg = ws;                         // 8192*128 fp32 = 4 MB
    float* Kg = ws + 1 * 1048576;
    float* Vg = ws + 2 * 1048576;
    float* Og = ws + 3 * 1048576;           // total 16 MB

    qkv_kernel<<<dim3(M_ROWS / 8, 3), 256, 0, stream>>>(x, Wq, Wk, Wv, Qg, Kg, Vg);
    attn_kernel<<<dim3(T_SEQ / 16, BATCH), 256, 0, stream>>>(Qg, Kg, Vg, Og);
    outproj_kernel<<<dim3(M_ROWS / 16, D_MODEL / 256), 256, 0, stream>>>(Og, Wo, out);
}

// Round 9
// 252.278 us; speedup vs baseline: 2.2439x; 2.1959x over previous
//
#include <hip/hip_runtime.h>

// B=4, T=2048, D=1024, DK=128. Inputs fp32, output fp32 (proven R0-R6).
// R8 pivot: bf16 MFMA everywhere (16x16x32), fp32 accumulate.
// Layouts (HW-verified per guide): A[m=lane&15][k=quad*8+j],
// B[n=lane&15][k=quad*8+j], C/D[col=lane&15][row=quad*4+reg].
#define BATCH 4
#define T_SEQ 2048
#define D_MODEL 1024
#define DK 128
#define M_ROWS 8192
#define SCALE 0.088388347648318447f     // 1/sqrt(128)

typedef __attribute__((ext_vector_type(8))) short short8;
typedef __attribute__((ext_vector_type(4))) float f32x4;

__device__ __forceinline__ unsigned short f2b(float f) {
    unsigned int x = __float_as_uint(f);
    return (unsigned short)((x + 0x7FFFu + ((x >> 16) & 1u)) >> 16);  // RNE
}

// ---------------------------------------------------------------------------
// prep_w: weights fp32 -> bf16, transposed to k-contiguous. grid (16,4), 256.
//   p<3 : Wt[p][n=128][k=1024] = W_p[k][n]
//   p==3: Wot[n=1024][k=128]   = Wo[k][n]
// ---------------------------------------------------------------------------
__global__ __launch_bounds__(256) void prep_w(
    const float* __restrict__ Wq, const float* __restrict__ Wk,
    const float* __restrict__ Wv, const float* __restrict__ Wo,
    unsigned short* __restrict__ Wt, unsigned short* __restrict__ Wot)
{
    __shared__ unsigned short t[64][130];   // stride 130 -> conflict-free col reads
    const int tid = threadIdx.x;
    const int p = blockIdx.y;
    if (p < 3) {
        const float* W = (p == 0) ? Wq : (p == 1) ? Wk : Wv;
        const int k0 = blockIdx.x * 64;
        for (int i = 0; i < 32; i++) {
            int idx = tid + 256 * i;            // 64x128
            int r = idx >> 7, c = idx & 127;
            t[r][c] = f2b(W[(size_t)(k0 + r) * DK + c]);
        }
        __syncthreads();
        unsigned short* outp = Wt + (size_t)p * DK * D_MODEL;
        for (int i = 0; i < 32; i++) {
            int idx = tid + 256 * i;            // 128n x 64k
            int n = idx >> 6, k = idx & 63;
            outp[(size_t)n * D_MODEL + k0 + k] = t[k][n];
        }
    } else {
        const int kt = blockIdx.x & 1, nt = blockIdx.x >> 1;
        const int k0 = kt * 64, n0 = nt * 128;
        for (int i = 0; i < 32; i++) {
            int idx = tid + 256 * i;
            int r = idx >> 7, c = idx & 127;
            t[r][c] = f2b(Wo[(size_t)(k0 + r) * D_MODEL + n0 + c]);
        }
        __syncthreads();
        for (int i = 0; i < 32; i++) {
            int idx = tid + 256 * i;            // 128n x 64k
            int n = idx >> 6, k = idx & 63;
            Wot[(size_t)(n0 + n) * DK + k0 + k] = t[k][n];
        }
    }
}

// ---------------------------------------------------------------------------
// qkv_mfma: grid (128,3), block 256 (4 waves). Tile 64 rows x 128 cols.
// p<2: D = x.W (Q/K, row-major bf16 out). p==2: D = Wv^T.x^T -> Vt[d][t].
// ---------------------------------------------------------------------------
__global__ __launch_bounds__(256) void qkv_mfma(
    const float* __restrict__ x, const unsigned short* __restrict__ Wt,
    unsigned short* __restrict__ Qb, unsigned short* __restrict__ Kb,
    unsigned short* __restrict__ Vt)
{
    const int p = blockIdx.y;
    const int row0 = blockIdx.x * 64;
    const int tid = threadIdx.x;
    const int w = tid >> 6, lane = tid & 63;
    const int l15 = lane & 15, quad = lane >> 4;

    __shared__ unsigned short xs[64][72];    // stride 144B: 16B-aligned, 2-way banks
    __shared__ unsigned short Ws[128][72];

    const unsigned short* Wp = Wt + (size_t)p * DK * D_MODEL;

    f32x4 acc[8];
    #pragma unroll
    for (int n = 0; n < 8; n++) acc[n] = (f32x4)(0.f);

    for (int k0 = 0; k0 < D_MODEL; k0 += 64) {
        #pragma unroll
        for (int i = 0; i < 4; i++) {           // x chunk 64r x 64k fp32->bf16
            int u = tid + 256 * i;              // 1024 float4 units
            int r = u >> 4, c4 = u & 15;
            float4 v = *(const float4*)(x + (size_t)(row0 + r) * D_MODEL + k0 + c4 * 4);
            *(ushort4*)&xs[r][c4 * 4] = make_ushort4(f2b(v.x), f2b(v.y), f2b(v.z), f2b(v.w));
        }
        #pragma unroll
        for (int i = 0; i < 8; i++) {           // W chunk 128n x 64k bf16 copy
            int u = tid + 256 * i;              // 2048 ushort4 units
            int n = u >> 4, c4 = u & 15;
            *(ushort4*)&Ws[n][c4 * 4] = *(const ushort4*)(Wp + (size_t)n * D_MODEL + k0 + c4 * 4);
        }
        __syncthreads();
        #pragma unroll
        for (int ks = 0; ks < 2; ks++) {
            short8 a = *(const short8*)&xs[16 * w + l15][ks * 32 + quad * 8];
            #pragma unroll
            for (int n = 0; n < 8; n++) {
                short8 bfr = *(const short8*)&Ws[n * 16 + l15][ks * 32 + quad * 8];
                if (p < 2)
                    acc[n] = __builtin_amdgcn_mfma_f32_16x16x32_bf16(a, bfr, acc[n], 0, 0, 0);
                else
                    acc[n] = __builtin_amdgcn_mfma_f32_16x16x32_bf16(bfr, a, acc[n], 0, 0, 0);
            }
        }
        __syncthreads();
    }

    if (p < 2) {
        unsigned short* outp = (p == 0) ? Qb : Kb;
        #pragma unroll
        for (int n = 0; n < 8; n++)
            #pragma unroll
            for (int r = 0; r < 4; r++)   // row=t=quad*4+r, col=d=n*16+l15
                outp[(size_t)(row0 + 16 * w + quad * 4 + r) * DK + n * 16 + l15] = f2b(acc[n][r]);
    } else {
        #pragma unroll
        for (int n = 0; n < 8; n++)
            #pragma unroll
            for (int r = 0; r < 4; r++)   // row=d=n*16+quad*4+r, col=t=16w+l15
                Vt[(size_t)(n * 16 + quad * 4 + r) * M_ROWS + row0 + 16 * w + l15] = f2b(acc[n][r]);
    }
}

// ---------------------------------------------------------------------------
// attn_mfma: grid 512, block 64 (1 wave). BQ=16 per block, BK=32 chunks.
// S^T = K.Q^T (so P lands as P[query][key-contig] in LDS); O = P.V via Vt.
// Register prefetch of next K/V chunk overlaps global latency with compute.
// ---------------------------------------------------------------------------
__global__ __launch_bounds__(64) void attn_mfma(
    const unsigned short* __restrict__ Qb, const unsigned short* __restrict__ Kb,
    const unsigned short* __restrict__ Vt, unsigned short* __restrict__ Ob)
{
    const int bid = blockIdx.x;
    const int qt = 127 - (bid >> 2);     // heavy q-tiles dispatch first
    const int b  = bid & 3;
    const int q0 = qt * 16;
    const int lane = threadIdx.x;
    const int l15 = lane & 15, quad = lane >> 4;

    __shared__ unsigned short Ksh[32][136];  // stride 272B: 16B-aligned, 2-way
    __shared__ unsigned short Vsh[128][40];  // stride 80B:  16B-aligned, 2-way
    __shared__ unsigned short Psh[16][40];

    short8 qf[4];                            // B-operand: [n=query=l15][k=dim]
    {
        const unsigned short* qp = Qb + (size_t)(b * T_SEQ + q0 + l15) * DK + quad * 8;
        #pragma unroll
        for (int ks = 0; ks < 4; ks++) qf[ks] = *(const short8*)(qp + ks * 32);
    }

    f32x4 of[8];
    #pragma unroll
    for (int n = 0; n < 8; n++) of[n] = (f32x4)(0.f);
    float m_s = -1e30f, l_s = 0.f;
    const int qg = q0 + l15;
    const int nch = qt / 2 + 1;

    uint4 kpre[8], vpre[8];                  // prefetch chunk 0
    #pragma unroll
    for (int i = 0; i < 8; i++) {
        int u = lane + 64 * i;
        int r = u >> 4, c = u & 15;          // K: 32 rows x 16 x 16B
        kpre[i] = *(const uint4*)(Kb + (size_t)(b * T_SEQ + r) * DK + c * 8);
        int d = u >> 2, cv = u & 3;          // V^T: 128 rows x 4 x 16B
        vpre[i] = *(const uint4*)(Vt + (size_t)d * M_ROWS + b * T_SEQ + cv * 8);
    }

    for (int ch = 0; ch < nch; ch++) {
        const int kc = ch * 32;
        __syncthreads();
        #pragma unroll
        for (int i = 0; i < 8; i++) {
            int u = lane + 64 * i;
            int r = u >> 4, c = u & 15;
            *(uint4*)&Ksh[r][c * 8] = kpre[i];
            int d = u >> 2, cv = u & 3;
            *(uint4*)&Vsh[d][cv * 8] = vpre[i];
        }
        __syncthreads();
        if (ch + 1 < nch) {
            const int kn = kc + 32;
            #pragma unroll
            for (int i = 0; i < 8; i++) {
                int u = lane + 64 * i;
                int r = u >> 4, c = u & 15;
                kpre[i] = *(const uint4*)(Kb + (size_t)(b * T_SEQ + kn + r) * DK + c * 8);
                int d = u >> 2, cv = u & 3;
                vpre[i] = *(const uint4*)(Vt + (size_t)d * M_ROWS + b * T_SEQ + kn + cv * 8);
            }
        }

        // S^T = K.Q^T : 2 key-subtiles x 4 k-steps
        f32x4 c0 = (f32x4)(0.f), c1 = (f32x4)(0.f);
        #pragma unroll
        for (int ks = 0; ks < 4; ks++) {
            short8 ka = *(const short8*)&Ksh[l15][ks * 32 + quad * 8];
            short8 kb = *(const short8*)&Ksh[16 + l15][ks * 32 + quad * 8];
            c0 = __builtin_amdgcn_mfma_f32_16x16x32_bf16(ka, qf[ks], c0, 0, 0, 0);
            c1 = __builtin_amdgcn_mfma_f32_16x16x32_bf16(kb, qf[ks], c1, 0, 0, 0);
        }

        // mask + online softmax. Lane owns query l15; keys at quad*4+r (+16).
        float s0[4], s1[4];
        float mx = -1e30f;
        #pragma unroll
        for (int r = 0; r < 4; r++) {
            int k0g = kc + quad * 4 + r;
            float v0 = (k0g      <= qg) ? c0[r] * SCALE : -1e30f;
            float v1 = (k0g + 16 <= qg) ? c1[r] * SCALE : -1e30f;
            s0[r] = v0; s1[r] = v1;
            mx = fmaxf(mx, fmaxf(v0, v1));
        }
        mx = fmaxf(mx, __shfl_xor(mx, 16, 64));
        mx = fmaxf(mx, __shfl_xor(mx, 32, 64));
        float m_new = fmaxf(m_s, mx);
        float alpha = __expf(m_s - m_new);
        float ls = 0.f;
        #pragma unroll
        for (int r = 0; r < 4; r++) {
            float p0 = __expf(s0[r] - m_new);
            float p1 = __expf(s1[r] - m_new);
            Psh[l15][quad * 4 + r]      = f2b(p0);
            Psh[l15][quad * 4 + r + 16] = f2b(p1);
            ls += p0 + p1;
        }
        ls += __shfl_xor(ls, 16, 64);
        ls += __shfl_xor(ls, 32, 64);
        l_s = l_s * alpha + ls;
        m_s = m_new;

        // rescale O rows (row = quad*4+r; alpha lives in lane quad*4+r)
        float alr[4];
        #pragma unroll
        for (int r = 0; r < 4; r++) alr[r] = __shfl(alpha, quad * 4 + r, 64);
        #pragma unroll
        for (int n = 0; n < 8; n++)
            #pragma unroll
            for (int r = 0; r < 4; r++) of[n][r] *= alr[r];

        __syncthreads();   // P visible
        short8 pf = *(const short8*)&Psh[l15][quad * 8];   // A: [m=query][k=key]
        #pragma unroll
        for (int n = 0; n < 8; n++) {
            short8 vf = *(const short8*)&Vsh[n * 16 + l15][quad * 8];  // B: [n=d][k=key]
            of[n] = __builtin_amdgcn_mfma_f32_16x16x32_bf16(pf, vf, of[n], 0, 0, 0);
        }
    }

    float invl[4];
    #pragma unroll
    for (int r = 0; r < 4; r++) invl[r] = 1.f / __shfl(l_s, quad * 4 + r, 64);
    #pragma unroll
    for (int n = 0; n < 8; n++)
        #pragma unroll
        for (int r = 0; r < 4; r++)
            Ob[(size_t)(b * T_SEQ + q0 + quad * 4 + r) * DK + n * 16 + l15] =
                f2b(of[n][r] * invl[r]);
}

// ---------------------------------------------------------------------------
// outproj_mfma: out(8192x1024 fp32) = Ob(bf16) . Wo. grid (128,4), block 256.
// ---------------------------------------------------------------------------
__global__ __launch_bounds__(256) void outproj_mfma(
    const unsigned short* __restrict__ Ob, const unsigned short* __restrict__ Wot,
    float* __restrict__ out)
{
    const int row0 = blockIdx.x * 64;
    const int nbase = blockIdx.y * 256;
    const int tid = threadIdx.x;
    const int w = tid >> 6, lane = tid & 63;
    const int l15 = lane & 15, quad = lane >> 4;

    __shared__ unsigned short Os[64][136];
    __shared__ unsigned short Wos[64][136];

    #pragma unroll
    for (int i = 0; i < 8; i++) {
        int u = tid + 256 * i;              // 2048 ushort4 units (64r x 128k)
        int r = u >> 5, c4 = u & 31;
        *(ushort4*)&Os[r][c4 * 4] = *(const ushort4*)(Ob + (size_t)(row0 + r) * DK + c4 * 4);
    }
    __syncthreads();

    short8 af[4];
    #pragma unroll
    for (int ks = 0; ks < 4; ks++)
        af[ks] = *(const short8*)&Os[16 * w + l15][ks * 32 + quad * 8];

    for (int nch = 0; nch < 4; nch++) {
        const int n0 = nbase + nch * 64;
        __syncthreads();
        #pragma unroll
        for (int i = 0; i < 8; i++) {
            int u = tid + 256 * i;
            int r = u >> 5, c4 = u & 31;
            *(ushort4*)&Wos[r][c4 * 4] = *(const ushort4*)(Wot + (size_t)(n0 + r) * DK + c4 * 4);
        }
        __syncthreads();
        f32x4 acc[4];
        #pragma unroll
        for (int n = 0; n < 4; n++) acc[n] = (f32x4)(0.f);
        #pragma unroll
        for (int ks = 0; ks < 4; ks++)
            #pragma unroll
            for (int n = 0; n < 4; n++) {
                short8 bf = *(const short8*)&Wos[n * 16 + l15][ks * 32 + quad * 8];
                acc[n] = __builtin_amdgcn_mfma_f32_16x16x32_bf16(af[ks], bf, acc[n], 0, 0, 0);
            }
        #pragma unroll
        for (int n = 0; n < 4; n++)
            #pragma unroll
            for (int r = 0; r < 4; r++)
                out[(size_t)(row0 + 16 * w + quad * 4 + r) * D_MODEL + n0 + n * 16 + l15] = acc[n][r];
    }
}

// ---------------------------------------------------------------------------
extern "C" void kernel_launch(void* const* d_in, const int* in_sizes, int n_in,
                              void* d_out, int out_size, void* d_ws, size_t ws_size,
                              hipStream_t stream)
{
    const float* x  = (const float*)d_in[0];
    const float* Wq = (const float*)d_in[1];
    const float* Wk = (const float*)d_in[2];
    const float* Wv = (const float*)d_in[3];
    const float* Wo = (const float*)d_in[4];
    float* out = (float*)d_out;

    unsigned short* ws  = (unsigned short*)d_ws;
    unsigned short* Qb  = ws;                    // [8192][128] bf16  (2 MB)
    unsigned short* Kb  = ws + 1048576;          // [8192][128]
    unsigned short* Vt  = ws + 2097152;          // [128][8192] (V transposed)
    unsigned short* Ob  = ws + 3145728;          // [8192][128]
    unsigned short* Wt  = ws + 4194304;          // [3][128][1024]
    unsigned short* Wot = ws + 4194304 + 393216; // [1024][128]   total ~9.4 MB

    prep_w     <<<dim3(16, 4),  256, 0, stream>>>(Wq, Wk, Wv, Wo, Wt, Wot);
    qkv_mfma   <<<dim3(128, 3), 256, 0, stream>>>(x, Wt, Qb, Kb, Vt);
    attn_mfma  <<<dim3(512),     64, 0, stream>>>(Qb, Kb, Vt, Ob);
    outproj_mfma<<<dim3(128, 4), 256, 0, stream>>>(Ob, Wot, out);
}